// Round 1
// baseline (2092.075 us; speedup 1.0000x reference)
//
#include <hip/hip_runtime.h>
#include <math.h>

#define NN 2048
#define MM 16384

// ---------------------------------------------------------------------------
// Phase 1: column partial sums  s_f[j] += sum_i tm[i]*exp(g[i] - 10*D[i,j])
// grid (MM/256, 8): blockIdx.x = column tile, blockIdx.y = row chunk (256 rows)
// ---------------------------------------------------------------------------
__global__ void k_f_partial(const float* __restrict__ dis,
                            const float* __restrict__ tm,
                            const float* __restrict__ g,
                            float* __restrict__ s_f,
                            const int* __restrict__ done) {
    if (*done) return;
    const int j  = blockIdx.x * 256 + threadIdx.x;
    const int i0 = blockIdx.y * (NN / 8);
    const float* p = dis + (size_t)i0 * MM + j;
    float acc = 0.f;
#pragma unroll 4
    for (int i = 0; i < NN / 8; ++i) {
        float d = p[(size_t)i * MM];              // coalesced across lanes
        float e = __expf(fmaf(d, -10.0f, g[i0 + i]));
        acc = fmaf(tm[i0 + i], e, acc);
    }
    atomicAdd(&s_f[j], acc);
}

// ---------------------------------------------------------------------------
// Phase 2: finalize f and reset the accumulator for the next iteration
// ---------------------------------------------------------------------------
__global__ void k_f_final(float* __restrict__ f,
                          float* __restrict__ s_f,
                          const int* __restrict__ done) {
    if (*done) return;
    const int j = blockIdx.x * 256 + threadIdx.x;
    f[j] = -__logf(s_f[j] + 1e-7f) * (1.0f / 1.1f);
    s_f[j] = 0.f;
}

// ---------------------------------------------------------------------------
// Phase 3: row reduction  g[i] = -log(sum_j pd[j]*exp(f[j] - 10*D[i,j]) + eps)
// one block per row; accumulate |g_new - g_old| into diff_acc
// ---------------------------------------------------------------------------
__global__ void k_g_row(const float* __restrict__ dis,
                        const float* __restrict__ pd,
                        const float* __restrict__ f,
                        float* __restrict__ g,
                        float* __restrict__ diff_acc,
                        const int* __restrict__ done) {
    if (*done) return;
    const int i = blockIdx.x;
    const float* p = dis + (size_t)i * MM;
    float acc = 0.f;
#pragma unroll 4
    for (int j = threadIdx.x; j < MM; j += 256) {
        float e = __expf(fmaf(p[j], -10.0f, f[j]));
        acc = fmaf(pd[j], e, acc);
    }
    __shared__ float red[256];
    red[threadIdx.x] = acc;
    __syncthreads();
    for (int s = 128; s > 0; s >>= 1) {
        if (threadIdx.x < s) red[threadIdx.x] += red[threadIdx.x + s];
        __syncthreads();
    }
    if (threadIdx.x == 0) {
        float gn = -__logf(red[0] + 1e-7f);
        atomicAdd(diff_acc, fabsf(gn - g[i]));
        g[i] = gn;
    }
}

// ---------------------------------------------------------------------------
// Phase 4: convergence check (matches: diff = SIGMA * mean|dg|; done |= diff<TOL)
// ---------------------------------------------------------------------------
__global__ void k_check(float* __restrict__ diff_acc, int* __restrict__ done) {
    if (!*done) {
        float diff = 0.1f * (*diff_acc / (float)NN);
        if (diff < 5e-4f) *done = 1;
    }
    *diff_acc = 0.f;
}

// ---------------------------------------------------------------------------
// Final transform: out[0..MM) = 1 - exp(-0.1*f); out[MM..MM+NN) = 0.1*g
// ---------------------------------------------------------------------------
__global__ void k_out(const float* __restrict__ f,
                      const float* __restrict__ g,
                      float* __restrict__ out) {
    const int idx = blockIdx.x * 256 + threadIdx.x;
    if (idx < MM) {
        out[idx] = 1.0f - __expf(-0.1f * f[idx]);
    } else if (idx < MM + NN) {
        out[idx] = 0.1f * g[idx - MM];
    }
}

extern "C" void kernel_launch(void* const* d_in, const int* in_sizes, int n_in,
                              void* d_out, int out_size, void* d_ws, size_t ws_size,
                              hipStream_t stream) {
    const float* dis = (const float*)d_in[0];   // (NN, MM) fp32
    const float* pd  = (const float*)d_in[1];   // (MM,)
    const float* tm  = (const float*)d_in[2];   // (NN,)
    float* out = (float*)d_out;                 // f (MM) then g (NN)

    float* g        = (float*)d_ws;             // NN
    float* f        = g + NN;                   // MM
    float* s_f      = f + MM;                   // MM
    float* diff_acc = s_f + MM;                 // 1
    int*   done     = (int*)(diff_acc + 1);     // 1

    // zero all iteration state (g=0, f=0, s_f=0, diff_acc=0, done=0)
    hipMemsetAsync(d_ws, 0, (size_t)(NN + 2 * MM + 2) * sizeof(float), stream);

    dim3 gridF(MM / 256, 8);
    for (int it = 0; it < 100; ++it) {
        k_f_partial<<<gridF, 256, 0, stream>>>(dis, tm, g, s_f, done);
        k_f_final<<<MM / 256, 256, 0, stream>>>(f, s_f, done);
        k_g_row<<<NN, 256, 0, stream>>>(dis, pd, f, g, diff_acc, done);
        k_check<<<1, 1, 0, stream>>>(diff_acc, done);
    }
    k_out<<<(MM + NN + 255) / 256, 256, 0, stream>>>(f, g, out);
}

// Round 3
// 1581.888 us; speedup vs baseline: 1.3225x; 1.3225x over previous
//
#include <hip/hip_runtime.h>
#include <math.h>

#define NN 2048
#define MM 16384

typedef __attribute__((ext_vector_type(8))) _Float16 f16x8;
typedef __attribute__((ext_vector_type(4))) float    f32x4;

// ===========================================================================
// Sinkhorn with precomputed fp16 kernel matrix.
//   K[i][j] = KT[j][i] = exp(-10*D[i][j])   (one-time prep)
//   phase A: f[j] = -log(dot(KT[j], w)+eps)/1.1 ; v[j] = pd[j]*exp(f[j])
//   phase B: g[i] = -log(dot(K[i],  v)+eps)     ; w[i] = tm[i]*exp(g[i])
//            + per-row |dg| -> diffpart; last block reduces deterministically
//            and sets done (freeze), emulating the torch break.
// ===========================================================================

__global__ void k_prep(const float* __restrict__ D,
                       _Float16* __restrict__ K,
                       _Float16* __restrict__ KT) {
    __shared__ _Float16 t[64][68];          // padded transpose stage
    const int bj = blockIdx.x;              // 256 column tiles
    const int bi = blockIdx.y;              // 32 row tiles
    const int c  = threadIdx.x & 63;
    const int r0 = threadIdx.x >> 6;
    const int i0 = bi * 64, j0 = bj * 64;
#pragma unroll
    for (int r = r0; r < 64; r += 4) {
        float d = D[(size_t)(i0 + r) * MM + j0 + c];
        _Float16 h = (_Float16)__expf(-10.0f * d);
        K[(size_t)(i0 + r) * MM + j0 + c] = h;
        t[c][r] = h;
    }
    __syncthreads();
#pragma unroll
    for (int r = r0; r < 64; r += 4)
        KT[(size_t)(j0 + r) * NN + i0 + c] = t[r][c];
}

__global__ void k_init(const float* __restrict__ tm,
                       float* __restrict__ g, float* __restrict__ w,
                       unsigned* __restrict__ counter, int* __restrict__ done) {
    const int i = blockIdx.x * 256 + threadIdx.x;
    if (i < NN) { g[i] = 0.0f; w[i] = tm[i]; }   // g=0 => w = tm*exp(0)
    if (i == 0) { *counter = 0u; *done = 0; }
}

// ---- phase A: 1024 blocks x 256 thr; wave handles 4 KT rows ---------------
__global__ __launch_bounds__(256)
void k_phaseA(const _Float16* __restrict__ KT, const float* __restrict__ pd,
              const float* __restrict__ w, float* __restrict__ f,
              float* __restrict__ v, const int* __restrict__ done) {
    if (*done) return;
    const int tid = threadIdx.x, lane = tid & 63, wid = tid >> 6;

    float wr[4][8];                          // register-cached slice of w
#pragma unroll
    for (int k = 0; k < 4; ++k) {
        const f32x4* p = (const f32x4*)(w + k * 512 + lane * 8);
        f32x4 a = p[0], b = p[1];
        wr[k][0] = a[0]; wr[k][1] = a[1]; wr[k][2] = a[2]; wr[k][3] = a[3];
        wr[k][4] = b[0]; wr[k][5] = b[1]; wr[k][6] = b[2]; wr[k][7] = b[3];
    }
    const int jbase = blockIdx.x * 16 + wid * 4;
#pragma unroll
    for (int r = 0; r < 4; ++r) {
        const int j = jbase + r;
        const _Float16* row = KT + (size_t)j * NN;
        float acc = 0.0f;
#pragma unroll
        for (int k = 0; k < 4; ++k) {
            f16x8 hv = *(const f16x8*)(row + k * 512 + lane * 8);
#pragma unroll
            for (int m = 0; m < 8; ++m)
                acc = fmaf((float)hv[m], wr[k][m], acc);
        }
#pragma unroll
        for (int s = 32; s; s >>= 1) acc += __shfl_xor(acc, s, 64);
        if (lane == 0) {
            float fj = -__logf(acc + 1e-7f) * (1.0f / 1.1f);
            f[j] = fj;
            v[j] = pd[j] * __expf(fj);
        }
    }
}

// ---- phase B: 1024 blocks x 256 thr; block handles 2 K rows ---------------
__global__ __launch_bounds__(256)
void k_phaseB(const _Float16* __restrict__ K, const float* __restrict__ tm,
              const float* __restrict__ v, float* __restrict__ g,
              float* __restrict__ w, float* __restrict__ diffpart,
              unsigned* __restrict__ counter, int* __restrict__ done) {
    if (*done) return;
    const int tid = threadIdx.x;
    const int i0  = blockIdx.x * 2;
    const _Float16* r0 = K + (size_t)i0 * MM;
    const _Float16* r1 = r0 + MM;

    float acc0 = 0.0f, acc1 = 0.0f;
#pragma unroll
    for (int p = 0; p < 8; ++p) {
        const int base = p * 2048 + tid * 8;
        const f32x4* vp = (const f32x4*)(v + base);
        f32x4 va = vp[0], vb = vp[1];
        f16x8 h0 = *(const f16x8*)(r0 + base);
        f16x8 h1 = *(const f16x8*)(r1 + base);
#pragma unroll
        for (int m = 0; m < 4; ++m) {
            acc0 = fmaf((float)h0[m], va[m], acc0);
            acc1 = fmaf((float)h1[m], va[m], acc1);
        }
#pragma unroll
        for (int m = 0; m < 4; ++m) {
            acc0 = fmaf((float)h0[4 + m], vb[m], acc0);
            acc1 = fmaf((float)h1[4 + m], vb[m], acc1);
        }
    }
    __shared__ float red0[256], red1[256];
    red0[tid] = acc0; red1[tid] = acc1;
    __syncthreads();
    for (int s = 128; s; s >>= 1) {
        if (tid < s) { red0[tid] += red0[tid + s]; red1[tid] += red1[tid + s]; }
        __syncthreads();
    }

    __shared__ bool last;
    if (tid == 0) {
        float gn0 = -__logf(red0[0] + 1e-7f);
        float gn1 = -__logf(red1[0] + 1e-7f);
        diffpart[i0]     = fabsf(gn0 - g[i0]);
        diffpart[i0 + 1] = fabsf(gn1 - g[i0 + 1]);
        g[i0]     = gn0;            g[i0 + 1] = gn1;
        w[i0]     = tm[i0]     * __expf(gn0);
        w[i0 + 1] = tm[i0 + 1] * __expf(gn1);
        __threadfence();                          // release diffpart/g/w
        unsigned old = atomicAdd(counter, 1u);
        last = (old == gridDim.x - 1);
    }
    __syncthreads();

    if (last) {                                   // deterministic check
        __threadfence();                          // acquire others' writes
        float s = 0.0f;
        for (int k2 = tid; k2 < NN; k2 += 256) s += diffpart[k2];
        red0[tid] = s;
        __syncthreads();
        for (int s2 = 128; s2; s2 >>= 1) {
            if (tid < s2) red0[tid] += red0[tid + s2];
            __syncthreads();
        }
        if (tid == 0) {
            if (0.1f * (red0[0] / (float)NN) < 5e-4f) *done = 1;
            *counter = 0u;                        // re-arm for next iteration
        }
    }
}

__global__ void k_out(const float* __restrict__ f,
                      const float* __restrict__ g,
                      float* __restrict__ out) {
    const int idx = blockIdx.x * 256 + threadIdx.x;
    if (idx < MM) {
        out[idx] = 1.0f - __expf(-0.1f * f[idx]);
    } else if (idx < MM + NN) {
        out[idx] = 0.1f * g[idx - MM];
    }
}

// ===========================================================================
// Legacy fallback (round-1 proven pipeline) if ws can't hold K + K^T.
// ===========================================================================
__global__ void k_f_partial(const float* __restrict__ dis,
                            const float* __restrict__ tm,
                            const float* __restrict__ g,
                            float* __restrict__ s_f,
                            const int* __restrict__ done) {
    if (*done) return;
    const int j  = blockIdx.x * 256 + threadIdx.x;
    const int i0 = blockIdx.y * (NN / 8);
    const float* p = dis + (size_t)i0 * MM + j;
    float acc = 0.f;
#pragma unroll 4
    for (int i = 0; i < NN / 8; ++i) {
        float d = p[(size_t)i * MM];
        float e = __expf(fmaf(d, -10.0f, g[i0 + i]));
        acc = fmaf(tm[i0 + i], e, acc);
    }
    atomicAdd(&s_f[j], acc);
}

__global__ void k_f_final(float* __restrict__ f, float* __restrict__ s_f,
                          const int* __restrict__ done) {
    if (*done) return;
    const int j = blockIdx.x * 256 + threadIdx.x;
    f[j] = -__logf(s_f[j] + 1e-7f) * (1.0f / 1.1f);
    s_f[j] = 0.f;
}

__global__ void k_g_row(const float* __restrict__ dis,
                        const float* __restrict__ pd,
                        const float* __restrict__ f,
                        float* __restrict__ g,
                        float* __restrict__ diff_acc,
                        const int* __restrict__ done) {
    if (*done) return;
    const int i = blockIdx.x;
    const float* p = dis + (size_t)i * MM;
    float acc = 0.f;
#pragma unroll 4
    for (int j = threadIdx.x; j < MM; j += 256) {
        float e = __expf(fmaf(p[j], -10.0f, f[j]));
        acc = fmaf(pd[j], e, acc);
    }
    __shared__ float red[256];
    red[threadIdx.x] = acc;
    __syncthreads();
    for (int s = 128; s > 0; s >>= 1) {
        if (threadIdx.x < s) red[threadIdx.x] += red[threadIdx.x + s];
        __syncthreads();
    }
    if (threadIdx.x == 0) {
        float gn = -__logf(red[0] + 1e-7f);
        atomicAdd(diff_acc, fabsf(gn - g[i]));
        g[i] = gn;
    }
}

__global__ void k_check(float* __restrict__ diff_acc, int* __restrict__ done) {
    if (!*done) {
        float diff = 0.1f * (*diff_acc / (float)NN);
        if (diff < 5e-4f) *done = 1;
    }
    *diff_acc = 0.f;
}

// ===========================================================================
extern "C" void kernel_launch(void* const* d_in, const int* in_sizes, int n_in,
                              void* d_out, int out_size, void* d_ws, size_t ws_size,
                              hipStream_t stream) {
    const float* dis = (const float*)d_in[0];   // (NN, MM) fp32
    const float* pd  = (const float*)d_in[1];   // (MM,)
    const float* tm  = (const float*)d_in[2];   // (NN,)
    float* out = (float*)d_out;

    const size_t kBytes = (size_t)NN * MM * sizeof(_Float16);   // 64 MiB each
    const size_t need   = 2 * kBytes
                        + (size_t)(2 * MM + 3 * NN) * sizeof(float) + 64;

    if (ws_size >= need) {
        _Float16* K  = (_Float16*)d_ws;
        _Float16* KT = (_Float16*)((char*)d_ws + kBytes);
        float* fbuf     = (float*)((char*)d_ws + 2 * kBytes);
        float* vbuf     = fbuf + MM;
        float* gbuf     = vbuf + MM;
        float* wbuf     = gbuf + NN;
        float* diffpart = wbuf + NN;            // NN floats
        unsigned* counter = (unsigned*)(diffpart + NN);
        int*      done    = (int*)(counter + 1);

        k_init<<<(NN + 255) / 256, 256, 0, stream>>>(tm, gbuf, wbuf, counter, done);
        k_prep<<<dim3(MM / 64, NN / 64), 256, 0, stream>>>(dis, K, KT);

        for (int it = 0; it < 100; ++it) {
            k_phaseA<<<1024, 256, 0, stream>>>(KT, pd, wbuf, fbuf, vbuf, done);
            k_phaseB<<<1024, 256, 0, stream>>>(K, tm, vbuf, gbuf, wbuf,
                                               diffpart, counter, done);
        }
        k_out<<<(MM + NN + 255) / 256, 256, 0, stream>>>(fbuf, gbuf, out);
    } else {
        // ---------------- legacy fallback ----------------
        float* g        = (float*)d_ws;
        float* f        = g + NN;
        float* s_f      = f + MM;
        float* diff_acc = s_f + MM;
        int*   done     = (int*)(diff_acc + 1);

        hipMemsetAsync(d_ws, 0, (size_t)(NN + 2 * MM + 2) * sizeof(float), stream);

        dim3 gridF(MM / 256, 8);
        for (int it = 0; it < 100; ++it) {
            k_f_partial<<<gridF, 256, 0, stream>>>(dis, tm, g, s_f, done);
            k_f_final<<<MM / 256, 256, 0, stream>>>(f, s_f, done);
            k_g_row<<<NN, 256, 0, stream>>>(dis, pd, f, g, diff_acc, done);
            k_check<<<1, 1, 0, stream>>>(diff_acc, done);
        }
        k_out<<<(MM + NN + 255) / 256, 256, 0, stream>>>(f, g, out);
    }
}

// Round 4
// 909.605 us; speedup vs baseline: 2.3000x; 1.7391x over previous
//
#include <hip/hip_runtime.h>
#include <math.h>

#define NN 2048
#define MM 16384

typedef __attribute__((ext_vector_type(4))) float f32x4;
typedef __attribute__((ext_vector_type(2))) float f32x2;

// ===========================================================================
// Sinkhorn with precomputed fp8(e4m3) kernel matrix (OCP, gfx950 native).
//   K8[i][j] = KT8[j][i] = fp8(exp(-10*D[i][j]))      (one-time prep)
//   phase A: f[j] = -log(dot(KT8[j], w)+eps)/1.1 ; v[j] = pd[j]*exp(f[j])
//   phase B: g[i] = -log(dot(K8[i],  v)+eps)     ; w[i] = tm[i]*exp(g[i])
//            + per-block |dg| partials; last block reduces deterministically
//            and sets done (freeze), emulating the torch break.
// ===========================================================================

__global__ __launch_bounds__(256)
void k_prep(const float* __restrict__ D,
            unsigned char* __restrict__ K8,
            unsigned char* __restrict__ KT8) {
    __shared__ unsigned char t[64][72];     // 72 % 4 == 0 -> aligned u32 reads
    const int j0 = blockIdx.x * 64, i0 = blockIdx.y * 64;
    const int tid = threadIdx.x;
    const int r = tid >> 4, c4 = tid & 15;  // 16 rows x 16 col-quads per pass
#pragma unroll
    for (int rp = 0; rp < 4; ++rp) {
        const int row = i0 + rp * 16 + r;
        f32x4 d = *(const f32x4*)(D + (size_t)row * MM + j0 + c4 * 4);
        float e0 = __expf(-10.0f * d[0]);
        float e1 = __expf(-10.0f * d[1]);
        float e2 = __expf(-10.0f * d[2]);
        float e3 = __expf(-10.0f * d[3]);
        int p = __builtin_amdgcn_cvt_pk_fp8_f32(e0, e1, 0, false);
        p = __builtin_amdgcn_cvt_pk_fp8_f32(e2, e3, p, true);
        *(unsigned*)(K8 + (size_t)row * MM + j0 + c4 * 4) = (unsigned)p;
        t[c4 * 4 + 0][rp * 16 + r] = (unsigned char)(p & 0xff);
        t[c4 * 4 + 1][rp * 16 + r] = (unsigned char)((p >> 8) & 0xff);
        t[c4 * 4 + 2][rp * 16 + r] = (unsigned char)((p >> 16) & 0xff);
        t[c4 * 4 + 3][rp * 16 + r] = (unsigned char)((p >> 24) & 0xff);
    }
    __syncthreads();
#pragma unroll
    for (int p2 = 0; p2 < 4; ++p2) {
        const int item = p2 * 256 + tid;          // 64 rows x 16 words
        const int jl = item >> 4, iw = item & 15;
        unsigned val = *(const unsigned*)&t[jl][iw * 4];
        *(unsigned*)(KT8 + (size_t)(j0 + jl) * NN + i0 + iw * 4) = val;
    }
}

__global__ void k_init(const float* __restrict__ tm,
                       float* __restrict__ g, float* __restrict__ w,
                       unsigned* __restrict__ counter, int* __restrict__ done) {
    const int i = blockIdx.x * 256 + threadIdx.x;
    if (i < NN) { g[i] = 0.0f; w[i] = tm[i]; }   // g=0 => w = tm*exp(0)
    if (i == 0) { *counter = 0u; *done = 0; }
}

// ---- phase A: 1024 blocks x 256 thr; each wave handles 4 KT rows ----------
__global__ __launch_bounds__(256, 2)
void k_phaseA(const unsigned char* __restrict__ KT8, const float* __restrict__ pd,
              const float* __restrict__ w, float* __restrict__ f,
              float* __restrict__ v, const int* __restrict__ done) {
    if (*done) return;
    const int tid = threadIdx.x, lane = tid & 63, wid = tid >> 6;

    float wr[2][16];                         // register-cached slice of w
#pragma unroll
    for (int k = 0; k < 2; ++k) {
        const f32x4* p = (const f32x4*)(w + k * 1024 + lane * 16);
#pragma unroll
        for (int q = 0; q < 4; ++q) {
            f32x4 a = p[q];
            wr[k][q * 4 + 0] = a[0]; wr[k][q * 4 + 1] = a[1];
            wr[k][q * 4 + 2] = a[2]; wr[k][q * 4 + 3] = a[3];
        }
    }
    const int jbase = blockIdx.x * 16 + wid * 4;
#pragma unroll
    for (int r = 0; r < 4; ++r) {
        const int j = jbase + r;
        const unsigned char* row = KT8 + (size_t)j * NN;
        float acc = 0.0f;
#pragma unroll
        for (int k = 0; k < 2; ++k) {
            uint4 qw = *(const uint4*)(row + k * 1024 + lane * 16);
            unsigned u[4] = {qw.x, qw.y, qw.z, qw.w};
#pragma unroll
            for (int c = 0; c < 4; ++c) {
                f32x2 lo = __builtin_amdgcn_cvt_pk_f32_fp8(u[c], false);
                f32x2 hi = __builtin_amdgcn_cvt_pk_f32_fp8(u[c], true);
                acc = fmaf(lo[0], wr[k][c * 4 + 0], acc);
                acc = fmaf(lo[1], wr[k][c * 4 + 1], acc);
                acc = fmaf(hi[0], wr[k][c * 4 + 2], acc);
                acc = fmaf(hi[1], wr[k][c * 4 + 3], acc);
            }
        }
#pragma unroll
        for (int s = 32; s; s >>= 1) acc += __shfl_xor(acc, s, 64);
        if (lane == 0) {
            float fj = -__logf(acc + 1e-7f) * (1.0f / 1.1f);
            f[j] = fj;
            v[j] = pd[j] * __expf(fj);
        }
    }
}

// ---- phase B: 512 blocks x 256 thr; block handles 4 K rows, v in regs -----
__global__ __launch_bounds__(256, 2)
void k_phaseB(const unsigned char* __restrict__ K8, const float* __restrict__ tm,
              const float* __restrict__ v, float* __restrict__ g,
              float* __restrict__ w, float* __restrict__ diffpart,
              unsigned* __restrict__ counter, int* __restrict__ done) {
    if (*done) return;
    const int tid = threadIdx.x;
    const int i0  = blockIdx.x * 4;

    float vr[4][16];                         // whole v register-cached (block)
#pragma unroll
    for (int k = 0; k < 4; ++k) {
        const f32x4* p = (const f32x4*)(v + k * 4096 + tid * 16);
#pragma unroll
        for (int q = 0; q < 4; ++q) {
            f32x4 a = p[q];
            vr[k][q * 4 + 0] = a[0]; vr[k][q * 4 + 1] = a[1];
            vr[k][q * 4 + 2] = a[2]; vr[k][q * 4 + 3] = a[3];
        }
    }
    f32x4 accv = {0.f, 0.f, 0.f, 0.f};
#pragma unroll
    for (int r = 0; r < 4; ++r) {
        const unsigned char* row = K8 + (size_t)(i0 + r) * MM;
        float acc = 0.0f;
#pragma unroll
        for (int k = 0; k < 4; ++k) {
            uint4 qw = *(const uint4*)(row + k * 4096 + tid * 16);
            unsigned u[4] = {qw.x, qw.y, qw.z, qw.w};
#pragma unroll
            for (int c = 0; c < 4; ++c) {
                f32x2 lo = __builtin_amdgcn_cvt_pk_f32_fp8(u[c], false);
                f32x2 hi = __builtin_amdgcn_cvt_pk_f32_fp8(u[c], true);
                acc = fmaf(lo[0], vr[k][c * 4 + 0], acc);
                acc = fmaf(lo[1], vr[k][c * 4 + 1], acc);
                acc = fmaf(hi[0], vr[k][c * 4 + 2], acc);
                acc = fmaf(hi[1], vr[k][c * 4 + 3], acc);
            }
        }
        accv[r] = acc;
    }
    __shared__ f32x4 red[256];
    red[tid] = accv;
    __syncthreads();
    for (int s = 128; s; s >>= 1) {
        if (tid < s) red[tid] += red[tid + s];
        __syncthreads();
    }
    __shared__ bool last;
    if (tid == 0) {
        f32x4 sv = red[0];
        float dp = 0.0f;
#pragma unroll
        for (int r = 0; r < 4; ++r) {
            float gn = -__logf(sv[r] + 1e-7f);
            dp += fabsf(gn - g[i0 + r]);
            g[i0 + r] = gn;
            w[i0 + r] = tm[i0 + r] * __expf(gn);
        }
        diffpart[blockIdx.x] = dp;
        __threadfence();                      // release diffpart/g/w
        unsigned old = atomicAdd(counter, 1u);
        last = (old == gridDim.x - 1);
    }
    __syncthreads();

    if (last) {                               // deterministic fixed-order check
        __threadfence();                      // acquire others' writes
        __shared__ float red1[256];
        red1[tid] = diffpart[tid] + diffpart[tid + 256];
        __syncthreads();
        for (int s2 = 128; s2; s2 >>= 1) {
            if (tid < s2) red1[tid] += red1[tid + s2];
            __syncthreads();
        }
        if (tid == 0) {
            if (0.1f * (red1[0] / (float)NN) < 5e-4f) *done = 1;
            *counter = 0u;                    // re-arm for next iteration
        }
    }
}

__global__ void k_out(const float* __restrict__ f,
                      const float* __restrict__ g,
                      float* __restrict__ out) {
    const int idx = blockIdx.x * 256 + threadIdx.x;
    if (idx < MM) {
        out[idx] = 1.0f - __expf(-0.1f * f[idx]);
    } else if (idx < MM + NN) {
        out[idx] = 0.1f * g[idx - MM];
    }
}

// ===========================================================================
// Legacy fallback (round-1 proven fp32 pipeline) if ws can't hold K8 + KT8.
// ===========================================================================
__global__ void k_f_partial(const float* __restrict__ dis,
                            const float* __restrict__ tm,
                            const float* __restrict__ g,
                            float* __restrict__ s_f,
                            const int* __restrict__ done) {
    if (*done) return;
    const int j  = blockIdx.x * 256 + threadIdx.x;
    const int i0 = blockIdx.y * (NN / 8);
    const float* p = dis + (size_t)i0 * MM + j;
    float acc = 0.f;
#pragma unroll 4
    for (int i = 0; i < NN / 8; ++i) {
        float d = p[(size_t)i * MM];
        float e = __expf(fmaf(d, -10.0f, g[i0 + i]));
        acc = fmaf(tm[i0 + i], e, acc);
    }
    atomicAdd(&s_f[j], acc);
}

__global__ void k_f_final(float* __restrict__ f, float* __restrict__ s_f,
                          const int* __restrict__ done) {
    if (*done) return;
    const int j = blockIdx.x * 256 + threadIdx.x;
    f[j] = -__logf(s_f[j] + 1e-7f) * (1.0f / 1.1f);
    s_f[j] = 0.f;
}

__global__ void k_g_row(const float* __restrict__ dis,
                        const float* __restrict__ pd,
                        const float* __restrict__ f,
                        float* __restrict__ g,
                        float* __restrict__ diff_acc,
                        const int* __restrict__ done) {
    if (*done) return;
    const int i = blockIdx.x;
    const float* p = dis + (size_t)i * MM;
    float acc = 0.f;
#pragma unroll 4
    for (int j = threadIdx.x; j < MM; j += 256) {
        float e = __expf(fmaf(p[j], -10.0f, f[j]));
        acc = fmaf(pd[j], e, acc);
    }
    __shared__ float red[256];
    red[threadIdx.x] = acc;
    __syncthreads();
    for (int s = 128; s > 0; s >>= 1) {
        if (threadIdx.x < s) red[threadIdx.x] += red[threadIdx.x + s];
        __syncthreads();
    }
    if (threadIdx.x == 0) {
        float gn = -__logf(red[0] + 1e-7f);
        atomicAdd(diff_acc, fabsf(gn - g[i]));
        g[i] = gn;
    }
}

__global__ void k_check(float* __restrict__ diff_acc, int* __restrict__ done) {
    if (!*done) {
        float diff = 0.1f * (*diff_acc / (float)NN);
        if (diff < 5e-4f) *done = 1;
    }
    *diff_acc = 0.f;
}

// ===========================================================================
extern "C" void kernel_launch(void* const* d_in, const int* in_sizes, int n_in,
                              void* d_out, int out_size, void* d_ws, size_t ws_size,
                              hipStream_t stream) {
    const float* dis = (const float*)d_in[0];   // (NN, MM) fp32
    const float* pd  = (const float*)d_in[1];   // (MM,)
    const float* tm  = (const float*)d_in[2];   // (NN,)
    float* out = (float*)d_out;

    const size_t kBytes = (size_t)NN * MM;      // 32 MiB each (fp8)
    const size_t need   = 2 * kBytes
                        + (size_t)(2 * MM + 3 * NN + 512) * sizeof(float) + 64;

    if (ws_size >= need) {
        unsigned char* K8  = (unsigned char*)d_ws;
        unsigned char* KT8 = (unsigned char*)d_ws + kBytes;
        float* fbuf     = (float*)((char*)d_ws + 2 * kBytes);
        float* vbuf     = fbuf + MM;
        float* gbuf     = vbuf + MM;
        float* wbuf     = gbuf + NN;
        float* diffpart = wbuf + NN;            // 512 floats
        unsigned* counter = (unsigned*)(diffpart + 512);
        int*      done    = (int*)(counter + 1);

        k_init<<<(NN + 255) / 256, 256, 0, stream>>>(tm, gbuf, wbuf, counter, done);
        k_prep<<<dim3(MM / 64, NN / 64), 256, 0, stream>>>(dis, K8, KT8);

        for (int it = 0; it < 100; ++it) {
            k_phaseA<<<1024, 256, 0, stream>>>(KT8, pd, wbuf, fbuf, vbuf, done);
            k_phaseB<<<512, 256, 0, stream>>>(K8, tm, vbuf, gbuf, wbuf,
                                              diffpart, counter, done);
        }
        k_out<<<(MM + NN + 255) / 256, 256, 0, stream>>>(fbuf, gbuf, out);
    } else {
        // ---------------- legacy fallback ----------------
        float* g        = (float*)d_ws;
        float* f        = g + NN;
        float* s_f      = f + MM;
        float* diff_acc = s_f + MM;
        int*   done     = (int*)(diff_acc + 1);

        hipMemsetAsync(d_ws, 0, (size_t)(NN + 2 * MM + 2) * sizeof(float), stream);

        dim3 gridF(MM / 256, 8);
        for (int it = 0; it < 100; ++it) {
            k_f_partial<<<gridF, 256, 0, stream>>>(dis, tm, g, s_f, done);
            k_f_final<<<MM / 256, 256, 0, stream>>>(f, s_f, done);
            k_g_row<<<NN, 256, 0, stream>>>(dis, pd, f, g, diff_acc, done);
            k_check<<<1, 1, 0, stream>>>(diff_acc, done);
        }
        k_out<<<(MM + NN + 255) / 256, 256, 0, stream>>>(f, g, out);
    }
}